// Round 1
// baseline (312.765 us; speedup 1.0000x reference)
//
#include <hip/hip_runtime.h>
#include <hip/hip_bf16.h>

#define IN_CH 128
#define OUT_CH 64
#define HEADS 2
#define NEG_SLOPE 0.2f

// ---------------------------------------------------------------------------
// Kernel 1: xh = x @ lin_w   (N x 128) = (N x 128)(128 x 128)
// Tile: 64 nodes x 128 channels per block, K chunked by 32 through LDS.
// Thread (ty,tx) = (tid/16, tid%16) computes nodes ty*4..+3, channels
// {tx*4..+3} and {64+tx*4..+3}  (both heads at the same d -> friendly stores).
// ---------------------------------------------------------------------------
#define TN 64
#define KB 32

__global__ __launch_bounds__(256) void gemm_kernel(
    const float* __restrict__ x, const float* __restrict__ lw,
    float* __restrict__ xh, int N) {
  __shared__ float sA[TN][KB + 4];     // 64 x 36 floats
  __shared__ float sB[KB][IN_CH + 4];  // 32 x 132 floats

  const int tid = threadIdx.x;
  const int n0 = blockIdx.x * TN;
  const int ty = tid >> 4;  // 0..15
  const int tx = tid & 15;  // 0..15

  float acc[4][8];
#pragma unroll
  for (int i = 0; i < 4; ++i)
#pragma unroll
    for (int j = 0; j < 8; ++j) acc[i][j] = 0.f;

  for (int kb = 0; kb < IN_CH; kb += KB) {
    // Load A tile: 64 rows x 32 k = 512 float4, 2 per thread.
#pragma unroll
    for (int l = 0; l < 2; ++l) {
      int f = tid + l * 256;
      int r = f >> 3;
      int c4 = (f & 7) << 2;
      int gr = n0 + r;
      float4 v = make_float4(0.f, 0.f, 0.f, 0.f);
      if (gr < N) v = *(const float4*)&x[(size_t)gr * IN_CH + kb + c4];
      *(float4*)&sA[r][c4] = v;
    }
    // Load B tile: 32 rows x 128 cols = 1024 float4, 4 per thread.
#pragma unroll
    for (int l = 0; l < 4; ++l) {
      int f = tid + l * 256;
      int r = f >> 5;
      int c4 = (f & 31) << 2;
      float4 v = *(const float4*)&lw[(size_t)(kb + r) * IN_CH + c4];
      *(float4*)&sB[r][c4] = v;
    }
    __syncthreads();

#pragma unroll
    for (int k = 0; k < KB; ++k) {
      float4 b0 = *(const float4*)&sB[k][tx * 4];
      float4 b1 = *(const float4*)&sB[k][64 + tx * 4];
#pragma unroll
      for (int i = 0; i < 4; ++i) {
        float a = sA[ty * 4 + i][k];
        acc[i][0] = fmaf(a, b0.x, acc[i][0]);
        acc[i][1] = fmaf(a, b0.y, acc[i][1]);
        acc[i][2] = fmaf(a, b0.z, acc[i][2]);
        acc[i][3] = fmaf(a, b0.w, acc[i][3]);
        acc[i][4] = fmaf(a, b1.x, acc[i][4]);
        acc[i][5] = fmaf(a, b1.y, acc[i][5]);
        acc[i][6] = fmaf(a, b1.z, acc[i][6]);
        acc[i][7] = fmaf(a, b1.w, acc[i][7]);
      }
    }
    __syncthreads();
  }

#pragma unroll
  for (int i = 0; i < 4; ++i) {
    int n = n0 + ty * 4 + i;
    if (n < N) {
      float4 v0 = make_float4(acc[i][0], acc[i][1], acc[i][2], acc[i][3]);
      float4 v1 = make_float4(acc[i][4], acc[i][5], acc[i][6], acc[i][7]);
      *(float4*)&xh[(size_t)n * IN_CH + tx * 4] = v0;
      *(float4*)&xh[(size_t)n * IN_CH + 64 + tx * 4] = v1;
    }
  }
}

// ---------------------------------------------------------------------------
// Kernel 2: per-node scores s_i, s_j [N,2] and self-loop init of w [N,2].
// One wave (64 lanes) per node; lane = channel d.
// ---------------------------------------------------------------------------
__global__ __launch_bounds__(256) void score_kernel(
    const float* __restrict__ xh, const float* __restrict__ emb,
    const float* __restrict__ att_i, const float* __restrict__ att_j,
    const float* __restrict__ att_em_i, const float* __restrict__ att_em_j,
    float2* __restrict__ si, float2* __restrict__ sj, float2* __restrict__ w,
    int N) {
  const int wave = threadIdx.x >> 6;
  const int lane = threadIdx.x & 63;
  const int n = blockIdx.x * 4 + wave;
  if (n >= N) return;

  float x0 = xh[(size_t)n * IN_CH + lane];
  float x1 = xh[(size_t)n * IN_CH + 64 + lane];
  float em = emb[(size_t)n * OUT_CH + lane];

  float v_si0 = fmaf(x0, att_i[lane], em * att_em_i[lane]);
  float v_si1 = fmaf(x1, att_i[64 + lane], em * att_em_i[64 + lane]);
  float v_sj0 = fmaf(x0, att_j[lane], em * att_em_j[lane]);
  float v_sj1 = fmaf(x1, att_j[64 + lane], em * att_em_j[64 + lane]);

#pragma unroll
  for (int off = 32; off > 0; off >>= 1) {
    v_si0 += __shfl_xor(v_si0, off, 64);
    v_si1 += __shfl_xor(v_si1, off, 64);
    v_sj0 += __shfl_xor(v_sj0, off, 64);
    v_sj1 += __shfl_xor(v_sj1, off, 64);
  }

  if (lane == 0) {
    si[n] = make_float2(v_si0, v_si1);
    sj[n] = make_float2(v_sj0, v_sj1);
    // self-loop edge n -> n
    float a0 = v_si0 + v_sj0;
    float a1 = v_si1 + v_sj1;
    a0 = a0 > 0.f ? a0 : NEG_SLOPE * a0;
    a1 = a1 > 0.f ? a1 : NEG_SLOPE * a1;
    float m = fmaxf(a0, a1);
    float p0 = __expf(a0 - m);
    float p1 = __expf(a1 - m);
    float inv = 1.f / (p0 + p1);
    w[n] = make_float2(p0 * inv, p1 * inv);
  }
}

// ---------------------------------------------------------------------------
// Kernel 3: edges — leaky_relu + softmax over heads, scatter-add alpha to w.
// ---------------------------------------------------------------------------
__global__ __launch_bounds__(256) void edge_kernel(
    const int* __restrict__ esrc, const int* __restrict__ edst,
    const float2* __restrict__ si, const float2* __restrict__ sj,
    float2* __restrict__ w, int E) {
  int e = blockIdx.x * 256 + threadIdx.x;
  if (e >= E) return;
  int s = esrc[e];
  int d = edst[e];
  float2 a = si[s];
  float2 b = sj[d];
  float a0 = a.x + b.x;
  float a1 = a.y + b.y;
  a0 = a0 > 0.f ? a0 : NEG_SLOPE * a0;
  a1 = a1 > 0.f ? a1 : NEG_SLOPE * a1;
  float m = fmaxf(a0, a1);
  float p0 = __expf(a0 - m);
  float p1 = __expf(a1 - m);
  float inv = 1.f / (p0 + p1);
  atomicAdd(&w[d].x, p0 * inv);
  atomicAdd(&w[d].y, p1 * inv);
}

// ---------------------------------------------------------------------------
// Kernel 4: out[n,d] = 0.5 * (xh[n,0,d]*w[n].x + xh[n,1,d]*w[n].y)
// ---------------------------------------------------------------------------
__global__ __launch_bounds__(256) void out_kernel(
    const float* __restrict__ xh, const float2* __restrict__ w,
    float* __restrict__ out, int N) {
  int t = blockIdx.x * 256 + threadIdx.x;
  if (t >= N * OUT_CH) return;
  int n = t >> 6;
  int d = t & 63;
  float2 ww = w[n];
  float v0 = xh[(size_t)n * IN_CH + d];
  float v1 = xh[(size_t)n * IN_CH + 64 + d];
  out[t] = 0.5f * fmaf(v0, ww.x, v1 * ww.y);
}

extern "C" void kernel_launch(void* const* d_in, const int* in_sizes, int n_in,
                              void* d_out, int out_size, void* d_ws,
                              size_t ws_size, hipStream_t stream) {
  const float* x = (const float*)d_in[0];
  const float* emb = (const float*)d_in[1];
  const float* lw = (const float*)d_in[2];
  const float* att_i = (const float*)d_in[3];
  const float* att_j = (const float*)d_in[4];
  const float* att_em_i = (const float*)d_in[5];
  const float* att_em_j = (const float*)d_in[6];
  const int* esrc = (const int*)d_in[7];
  const int* edst = (const int*)d_in[8];
  float* out = (float*)d_out;

  const int N = in_sizes[0] / IN_CH;  // 50000
  const int E = in_sizes[7];          // 1600000

  char* ws = (char*)d_ws;
  float* xh = (float*)ws;                            // N*128 floats
  float2* si = (float2*)(ws + (size_t)N * IN_CH * 4);  // N float2
  float2* sj = si + N;
  float2* w = sj + N;

  gemm_kernel<<<dim3((N + TN - 1) / TN), dim3(256), 0, stream>>>(x, lw, xh, N);
  score_kernel<<<dim3((N + 3) / 4), dim3(256), 0, stream>>>(
      xh, emb, att_i, att_j, att_em_i, att_em_j, si, sj, w, N);
  edge_kernel<<<dim3((E + 255) / 256), dim3(256), 0, stream>>>(esrc, edst, si,
                                                               sj, w, E);
  out_kernel<<<dim3((N * OUT_CH + 255) / 256), dim3(256), 0, stream>>>(xh, w,
                                                                       out, N);
}

// Round 2
// 310.302 us; speedup vs baseline: 1.0079x; 1.0079x over previous
//
#include <hip/hip_runtime.h>
#include <hip/hip_bf16.h>

#define IN_CH 128
#define OUT_CH 64
#define HEADS 2
#define NEG_SLOPE 0.2f

// ---------------------------------------------------------------------------
// Kernel 1: xh = x @ lin_w   (N x 128) = (N x 128)(128 x 128)
// Tile: 64 nodes x 128 channels per block, K chunked by 32 through LDS.
// ---------------------------------------------------------------------------
#define TN 64
#define KB 32

__global__ __launch_bounds__(256) void gemm_kernel(
    const float* __restrict__ x, const float* __restrict__ lw,
    float* __restrict__ xh, int N) {
  __shared__ float sA[TN][KB + 4];     // 64 x 36 floats
  __shared__ float sB[KB][IN_CH + 4];  // 32 x 132 floats

  const int tid = threadIdx.x;
  const int n0 = blockIdx.x * TN;
  const int ty = tid >> 4;  // 0..15
  const int tx = tid & 15;  // 0..15

  float acc[4][8];
#pragma unroll
  for (int i = 0; i < 4; ++i)
#pragma unroll
    for (int j = 0; j < 8; ++j) acc[i][j] = 0.f;

  for (int kb = 0; kb < IN_CH; kb += KB) {
    // Load A tile: 64 rows x 32 k = 512 float4, 2 per thread.
#pragma unroll
    for (int l = 0; l < 2; ++l) {
      int f = tid + l * 256;
      int r = f >> 3;
      int c4 = (f & 7) << 2;
      int gr = n0 + r;
      float4 v = make_float4(0.f, 0.f, 0.f, 0.f);
      if (gr < N) v = *(const float4*)&x[(size_t)gr * IN_CH + kb + c4];
      *(float4*)&sA[r][c4] = v;
    }
    // Load B tile: 32 rows x 128 cols = 1024 float4, 4 per thread.
#pragma unroll
    for (int l = 0; l < 4; ++l) {
      int f = tid + l * 256;
      int r = f >> 5;
      int c4 = (f & 31) << 2;
      float4 v = *(const float4*)&lw[(size_t)(kb + r) * IN_CH + c4];
      *(float4*)&sB[r][c4] = v;
    }
    __syncthreads();

#pragma unroll
    for (int k = 0; k < KB; ++k) {
      float4 b0 = *(const float4*)&sB[k][tx * 4];
      float4 b1 = *(const float4*)&sB[k][64 + tx * 4];
#pragma unroll
      for (int i = 0; i < 4; ++i) {
        float a = sA[ty * 4 + i][k];
        acc[i][0] = fmaf(a, b0.x, acc[i][0]);
        acc[i][1] = fmaf(a, b0.y, acc[i][1]);
        acc[i][2] = fmaf(a, b0.z, acc[i][2]);
        acc[i][3] = fmaf(a, b0.w, acc[i][3]);
        acc[i][4] = fmaf(a, b1.x, acc[i][4]);
        acc[i][5] = fmaf(a, b1.y, acc[i][5]);
        acc[i][6] = fmaf(a, b1.z, acc[i][6]);
        acc[i][7] = fmaf(a, b1.w, acc[i][7]);
      }
    }
    __syncthreads();
  }

#pragma unroll
  for (int i = 0; i < 4; ++i) {
    int n = n0 + ty * 4 + i;
    if (n < N) {
      float4 v0 = make_float4(acc[i][0], acc[i][1], acc[i][2], acc[i][3]);
      float4 v1 = make_float4(acc[i][4], acc[i][5], acc[i][6], acc[i][7]);
      *(float4*)&xh[(size_t)n * IN_CH + tx * 4] = v0;
      *(float4*)&xh[(size_t)n * IN_CH + 64 + tx * 4] = v1;
    }
  }
}

// ---------------------------------------------------------------------------
// Kernel 2: per-node scores s_i, s_j [N,2] and self-loop init of w [N,2].
// One wave (64 lanes) per node; lane = channel d.
// ---------------------------------------------------------------------------
__global__ __launch_bounds__(256) void score_kernel(
    const float* __restrict__ xh, const float* __restrict__ emb,
    const float* __restrict__ att_i, const float* __restrict__ att_j,
    const float* __restrict__ att_em_i, const float* __restrict__ att_em_j,
    float2* __restrict__ si, float2* __restrict__ sj, float2* __restrict__ w,
    int N) {
  const int wave = threadIdx.x >> 6;
  const int lane = threadIdx.x & 63;
  const int n = blockIdx.x * 4 + wave;
  if (n >= N) return;

  float x0 = xh[(size_t)n * IN_CH + lane];
  float x1 = xh[(size_t)n * IN_CH + 64 + lane];
  float em = emb[(size_t)n * OUT_CH + lane];

  float v_si0 = fmaf(x0, att_i[lane], em * att_em_i[lane]);
  float v_si1 = fmaf(x1, att_i[64 + lane], em * att_em_i[64 + lane]);
  float v_sj0 = fmaf(x0, att_j[lane], em * att_em_j[lane]);
  float v_sj1 = fmaf(x1, att_j[64 + lane], em * att_em_j[64 + lane]);

#pragma unroll
  for (int off = 32; off > 0; off >>= 1) {
    v_si0 += __shfl_xor(v_si0, off, 64);
    v_si1 += __shfl_xor(v_si1, off, 64);
    v_sj0 += __shfl_xor(v_sj0, off, 64);
    v_sj1 += __shfl_xor(v_sj1, off, 64);
  }

  if (lane == 0) {
    si[n] = make_float2(v_si0, v_si1);
    sj[n] = make_float2(v_sj0, v_sj1);
    // self-loop edge n -> n
    float a0 = v_si0 + v_sj0;
    float a1 = v_si1 + v_sj1;
    a0 = a0 > 0.f ? a0 : NEG_SLOPE * a0;
    a1 = a1 > 0.f ? a1 : NEG_SLOPE * a1;
    // softmax over 2 heads: p0 = 1/(1+exp(a1-a0))
    float p0 = 1.f / (1.f + __expf(a1 - a0));
    w[n] = make_float2(p0, 1.f - p0);
  }
}

// ---------------------------------------------------------------------------
// Kernel 3: edges — leaky_relu + softmax over heads, scatter-add alpha to w.
// unsafeAtomicAdd -> native global_atomic_add_f32 (no CAS retry loop).
// ---------------------------------------------------------------------------
__global__ __launch_bounds__(256) void edge_kernel(
    const int* __restrict__ esrc, const int* __restrict__ edst,
    const float2* __restrict__ si, const float2* __restrict__ sj,
    float* __restrict__ w, int E) {
  int e = blockIdx.x * 256 + threadIdx.x;
  if (e >= E) return;
  int s = esrc[e];
  int d = edst[e];
  float2 a = si[s];
  float2 b = sj[d];
  float a0 = a.x + b.x;
  float a1 = a.y + b.y;
  a0 = a0 > 0.f ? a0 : NEG_SLOPE * a0;
  a1 = a1 > 0.f ? a1 : NEG_SLOPE * a1;
  float p0 = 1.f / (1.f + __expf(a1 - a0));
  unsafeAtomicAdd(&w[2 * (size_t)d + 0], p0);
  unsafeAtomicAdd(&w[2 * (size_t)d + 1], 1.f - p0);
}

// ---------------------------------------------------------------------------
// Kernel 4: out[n,d] = 0.5 * (xh[n,0,d]*w[n].x + xh[n,1,d]*w[n].y)
// ---------------------------------------------------------------------------
__global__ __launch_bounds__(256) void out_kernel(
    const float* __restrict__ xh, const float2* __restrict__ w,
    float* __restrict__ out, int N) {
  int t = blockIdx.x * 256 + threadIdx.x;
  if (t >= N * OUT_CH) return;
  int n = t >> 6;
  int d = t & 63;
  float2 ww = w[n];
  float v0 = xh[(size_t)n * IN_CH + d];
  float v1 = xh[(size_t)n * IN_CH + 64 + d];
  out[t] = 0.5f * fmaf(v0, ww.x, v1 * ww.y);
}

extern "C" void kernel_launch(void* const* d_in, const int* in_sizes, int n_in,
                              void* d_out, int out_size, void* d_ws,
                              size_t ws_size, hipStream_t stream) {
  const float* x = (const float*)d_in[0];
  const float* emb = (const float*)d_in[1];
  const float* lw = (const float*)d_in[2];
  const float* att_i = (const float*)d_in[3];
  const float* att_j = (const float*)d_in[4];
  const float* att_em_i = (const float*)d_in[5];
  const float* att_em_j = (const float*)d_in[6];
  const int* esrc = (const int*)d_in[7];
  const int* edst = (const int*)d_in[8];
  float* out = (float*)d_out;

  const int N = in_sizes[0] / IN_CH;  // 50000
  const int E = in_sizes[7];          // 1600000

  char* ws = (char*)d_ws;
  float* xh = (float*)ws;                              // N*128 floats
  float2* si = (float2*)(ws + (size_t)N * IN_CH * 4);  // N float2
  float2* sj = si + N;
  float2* w = sj + N;

  gemm_kernel<<<dim3((N + TN - 1) / TN), dim3(256), 0, stream>>>(x, lw, xh, N);
  score_kernel<<<dim3((N + 3) / 4), dim3(256), 0, stream>>>(
      xh, emb, att_i, att_j, att_em_i, att_em_j, si, sj, w, N);
  edge_kernel<<<dim3((E + 255) / 256), dim3(256), 0, stream>>>(
      esrc, edst, si, sj, (float*)w, E);
  out_kernel<<<dim3((N * OUT_CH + 255) / 256), dim3(256), 0, stream>>>(xh, w,
                                                                       out, N);
}

// Round 3
// 305.441 us; speedup vs baseline: 1.0240x; 1.0159x over previous
//
#include <hip/hip_runtime.h>
#include <hip/hip_bf16.h>

#define IN_CH 128
#define OUT_CH 64
#define HEADS 2
#define NEG_SLOPE 0.2f
#define NXCD 8

// ---------------------------------------------------------------------------
// Kernel 1: xh = x @ lin_w   (N x 128) = (N x 128)(128 x 128)
// Tile: 64 nodes x 128 channels per block, K chunked by 32 through LDS.
// ---------------------------------------------------------------------------
#define TN 64
#define KB 32

__global__ __launch_bounds__(256) void gemm_kernel(
    const float* __restrict__ x, const float* __restrict__ lw,
    float* __restrict__ xh, int N) {
  __shared__ float sA[TN][KB + 4];     // 64 x 36 floats
  __shared__ float sB[KB][IN_CH + 4];  // 32 x 132 floats

  const int tid = threadIdx.x;
  const int n0 = blockIdx.x * TN;
  const int ty = tid >> 4;  // 0..15
  const int tx = tid & 15;  // 0..15

  float acc[4][8];
#pragma unroll
  for (int i = 0; i < 4; ++i)
#pragma unroll
    for (int j = 0; j < 8; ++j) acc[i][j] = 0.f;

  for (int kb = 0; kb < IN_CH; kb += KB) {
#pragma unroll
    for (int l = 0; l < 2; ++l) {
      int f = tid + l * 256;
      int r = f >> 3;
      int c4 = (f & 7) << 2;
      int gr = n0 + r;
      float4 v = make_float4(0.f, 0.f, 0.f, 0.f);
      if (gr < N) v = *(const float4*)&x[(size_t)gr * IN_CH + kb + c4];
      *(float4*)&sA[r][c4] = v;
    }
#pragma unroll
    for (int l = 0; l < 4; ++l) {
      int f = tid + l * 256;
      int r = f >> 5;
      int c4 = (f & 31) << 2;
      float4 v = *(const float4*)&lw[(size_t)(kb + r) * IN_CH + c4];
      *(float4*)&sB[r][c4] = v;
    }
    __syncthreads();

#pragma unroll
    for (int k = 0; k < KB; ++k) {
      float4 b0 = *(const float4*)&sB[k][tx * 4];
      float4 b1 = *(const float4*)&sB[k][64 + tx * 4];
#pragma unroll
      for (int i = 0; i < 4; ++i) {
        float a = sA[ty * 4 + i][k];
        acc[i][0] = fmaf(a, b0.x, acc[i][0]);
        acc[i][1] = fmaf(a, b0.y, acc[i][1]);
        acc[i][2] = fmaf(a, b0.z, acc[i][2]);
        acc[i][3] = fmaf(a, b0.w, acc[i][3]);
        acc[i][4] = fmaf(a, b1.x, acc[i][4]);
        acc[i][5] = fmaf(a, b1.y, acc[i][5]);
        acc[i][6] = fmaf(a, b1.z, acc[i][6]);
        acc[i][7] = fmaf(a, b1.w, acc[i][7]);
      }
    }
    __syncthreads();
  }

#pragma unroll
  for (int i = 0; i < 4; ++i) {
    int n = n0 + ty * 4 + i;
    if (n < N) {
      float4 v0 = make_float4(acc[i][0], acc[i][1], acc[i][2], acc[i][3]);
      float4 v1 = make_float4(acc[i][4], acc[i][5], acc[i][6], acc[i][7]);
      *(float4*)&xh[(size_t)n * IN_CH + tx * 4] = v0;
      *(float4*)&xh[(size_t)n * IN_CH + 64 + tx * 4] = v1;
    }
  }
}

// ---------------------------------------------------------------------------
// Kernel 2: per-node scores s_i, s_j [N,2]; seed w with the self-loop alpha.
// ---------------------------------------------------------------------------
__global__ __launch_bounds__(256) void score_kernel(
    const float* __restrict__ xh, const float* __restrict__ emb,
    const float* __restrict__ att_i, const float* __restrict__ att_j,
    const float* __restrict__ att_em_i, const float* __restrict__ att_em_j,
    float2* __restrict__ si, float2* __restrict__ sj, float2* __restrict__ w,
    int N) {
  const int wave = threadIdx.x >> 6;
  const int lane = threadIdx.x & 63;
  const int n = blockIdx.x * 4 + wave;
  if (n >= N) return;

  float x0 = xh[(size_t)n * IN_CH + lane];
  float x1 = xh[(size_t)n * IN_CH + 64 + lane];
  float em = emb[(size_t)n * OUT_CH + lane];

  float v_si0 = fmaf(x0, att_i[lane], em * att_em_i[lane]);
  float v_si1 = fmaf(x1, att_i[64 + lane], em * att_em_i[64 + lane]);
  float v_sj0 = fmaf(x0, att_j[lane], em * att_em_j[lane]);
  float v_sj1 = fmaf(x1, att_j[64 + lane], em * att_em_j[64 + lane]);

#pragma unroll
  for (int off = 32; off > 0; off >>= 1) {
    v_si0 += __shfl_xor(v_si0, off, 64);
    v_si1 += __shfl_xor(v_si1, off, 64);
    v_sj0 += __shfl_xor(v_sj0, off, 64);
    v_sj1 += __shfl_xor(v_sj1, off, 64);
  }

  if (lane == 0) {
    si[n] = make_float2(v_si0, v_si1);
    sj[n] = make_float2(v_sj0, v_sj1);
    float a0 = v_si0 + v_sj0;
    float a1 = v_si1 + v_sj1;
    a0 = a0 > 0.f ? a0 : NEG_SLOPE * a0;
    a1 = a1 > 0.f ? a1 : NEG_SLOPE * a1;
    float p0 = 1.f / (1.f + __expf(a1 - a0));
    w[n] = make_float2(p0, 1.f - p0);
  }
}

// ---------------------------------------------------------------------------
// Kernel 3: edges. Atomics into the *XCD-local* replica of w with
// workgroup scope -> global_atomic_add_f32 without sc1 -> executes in this
// XCD's L2 (coherent within the XCD; replica is only ever touched by its
// own XCD, so that suffices). End-of-kernel release writes L2 back.
// ---------------------------------------------------------------------------
__device__ __forceinline__ int xcc_id() {
  int x;
  // HW_REG_XCC_ID = hwreg 20 on gfx940+/gfx950; field is bits [3:0].
  asm volatile("s_getreg_b32 %0, hwreg(20, 0, 4)" : "=s"(x));
  return x & (NXCD - 1);
}

__global__ __launch_bounds__(256) void edge_kernel(
    const int* __restrict__ esrc, const int* __restrict__ edst,
    const float2* __restrict__ si, const float2* __restrict__ sj,
    float* __restrict__ w_rep, int N, int E) {
  int e = blockIdx.x * 256 + threadIdx.x;
  if (e >= E) return;
  float* rep = w_rep + (size_t)xcc_id() * N * 2;
  int s = esrc[e];
  int d = edst[e];
  float2 a = si[s];
  float2 b = sj[d];
  float a0 = a.x + b.x;
  float a1 = a.y + b.y;
  a0 = a0 > 0.f ? a0 : NEG_SLOPE * a0;
  a1 = a1 > 0.f ? a1 : NEG_SLOPE * a1;
  float p0 = 1.f / (1.f + __expf(a1 - a0));
  __hip_atomic_fetch_add(&rep[2 * (size_t)d + 0], p0, __ATOMIC_RELAXED,
                         __HIP_MEMORY_SCOPE_WORKGROUP);
  __hip_atomic_fetch_add(&rep[2 * (size_t)d + 1], 1.f - p0, __ATOMIC_RELAXED,
                         __HIP_MEMORY_SCOPE_WORKGROUP);
}

// ---------------------------------------------------------------------------
// Kernel 3b: fold the 8 replicas into w (w already holds the self-loop term).
// ---------------------------------------------------------------------------
__global__ __launch_bounds__(256) void reduce_w_kernel(
    const float2* __restrict__ w_rep, float2* __restrict__ w, int N) {
  int n = blockIdx.x * 256 + threadIdx.x;
  if (n >= N) return;
  float2 acc = w[n];
#pragma unroll
  for (int r = 0; r < NXCD; ++r) {
    float2 v = w_rep[(size_t)r * N + n];
    acc.x += v.x;
    acc.y += v.y;
  }
  w[n] = acc;
}

// ---------------------------------------------------------------------------
// Kernel 4: out[n,d] = 0.5 * (xh[n,0,d]*w[n].x + xh[n,1,d]*w[n].y)
// ---------------------------------------------------------------------------
__global__ __launch_bounds__(256) void out_kernel(
    const float* __restrict__ xh, const float2* __restrict__ w,
    float* __restrict__ out, int N) {
  int t = blockIdx.x * 256 + threadIdx.x;
  if (t >= N * OUT_CH) return;
  int n = t >> 6;
  int d = t & 63;
  float2 ww = w[n];
  float v0 = xh[(size_t)n * IN_CH + d];
  float v1 = xh[(size_t)n * IN_CH + 64 + d];
  out[t] = 0.5f * fmaf(v0, ww.x, v1 * ww.y);
}

extern "C" void kernel_launch(void* const* d_in, const int* in_sizes, int n_in,
                              void* d_out, int out_size, void* d_ws,
                              size_t ws_size, hipStream_t stream) {
  const float* x = (const float*)d_in[0];
  const float* emb = (const float*)d_in[1];
  const float* lw = (const float*)d_in[2];
  const float* att_i = (const float*)d_in[3];
  const float* att_j = (const float*)d_in[4];
  const float* att_em_i = (const float*)d_in[5];
  const float* att_em_j = (const float*)d_in[6];
  const int* esrc = (const int*)d_in[7];
  const int* edst = (const int*)d_in[8];
  float* out = (float*)d_out;

  const int N = in_sizes[0] / IN_CH;  // 50000
  const int E = in_sizes[7];          // 1600000

  char* ws = (char*)d_ws;
  float* xh = (float*)ws;                              // N*128 f  (25.6 MB)
  float2* si = (float2*)(ws + (size_t)N * IN_CH * 4);  // N float2
  float2* sj = si + N;
  float2* w = sj + N;
  float2* w_rep = w + N;  // 8 * N float2 (3.2 MB); 128B-aligned per replica

  hipMemsetAsync(w_rep, 0, (size_t)NXCD * N * sizeof(float2), stream);
  gemm_kernel<<<dim3((N + TN - 1) / TN), dim3(256), 0, stream>>>(x, lw, xh, N);
  score_kernel<<<dim3((N + 3) / 4), dim3(256), 0, stream>>>(
      xh, emb, att_i, att_j, att_em_i, att_em_j, si, sj, w, N);
  edge_kernel<<<dim3((E + 255) / 256), dim3(256), 0, stream>>>(
      esrc, edst, si, sj, (float*)w_rep, N, E);
  reduce_w_kernel<<<dim3((N + 255) / 256), dim3(256), 0, stream>>>(w_rep, w, N);
  out_kernel<<<dim3((N * OUT_CH + 255) / 256), dim3(256), 0, stream>>>(xh, w,
                                                                       out, N);
}

// Round 4
// 234.626 us; speedup vs baseline: 1.3330x; 1.3018x over previous
//
#include <hip/hip_runtime.h>
#include <hip/hip_bf16.h>

#define IN_CH 128
#define OUT_CH 64
#define NEG_SLOPE 0.2f
// Packing constant: each edge atomically adds (KPACK + p0) to wsum[dst].
// cnt = floor(ws/KPACK), sum_p0 = ws - KPACK*cnt, w1 = cnt - sum_p0.
// KPACK = 1024.5 keeps frac strictly in (0.5*cnt, 1.5*cnt) ⊂ (0, KPACK).
#define KPACK 1024.5f

typedef short bf16x8 __attribute__((ext_vector_type(8)));
typedef float f32x4 __attribute__((ext_vector_type(4)));

__device__ __forceinline__ unsigned short f2bf(float f) {
  union { float f; unsigned u; } v;
  v.f = f;
  unsigned r = v.u + 0x7FFF + ((v.u >> 16) & 1);  // RNE
  return (unsigned short)(r >> 16);
}

// ---------------------------------------------------------------------------
// Kernel 0: lwt[c][k] = bf16(lw[k][c])  (transposed 128x128 bf16 table, 32KB)
// ---------------------------------------------------------------------------
__global__ __launch_bounds__(256) void transpose_lw_kernel(
    const float* __restrict__ lw, unsigned short* __restrict__ lwt) {
  int idx = blockIdx.x * 256 + threadIdx.x;  // 0..16383
  int k = idx >> 7;
  int c = idx & 127;
  lwt[(size_t)c * IN_CH + k] = f2bf(lw[idx]);
}

// ---------------------------------------------------------------------------
// Kernel 1: xh = x @ lin_w via bf16 MFMA 16x16x32.
// Block = 256 thr = 4 waves; wave handles 16 rows x 128 cols; K = 128 in 4 steps.
// A-frag: lane holds A[m=lane&15][k=(lane>>4)*8 + 0..7] (8 contiguous k).
// B-frag: lane holds B[k=(lane>>4)*8 + 0..7][n=lane&15] -> contiguous in lwt.
// C/D:    col=lane&15, row=(lane>>4)*4+reg.
// ---------------------------------------------------------------------------
__global__ __launch_bounds__(256) void mfma_gemm_kernel(
    const float* __restrict__ x, const unsigned short* __restrict__ lwt,
    float* __restrict__ xh, int N) {
  const int wave = threadIdx.x >> 6;
  const int lane = threadIdx.x & 63;
  const int row0 = blockIdx.x * 64 + wave * 16;
  int arow = row0 + (lane & 15);
  if (arow >= N) arow = N - 1;  // clamped read; stores are guarded
  const int ko = (lane >> 4) * 8;

  const float* ap = x + (size_t)arow * IN_CH + ko;
  bf16x8 a[4];
#pragma unroll
  for (int kb = 0; kb < 4; ++kb) {
    float4 f0 = *(const float4*)(ap + kb * 32);
    float4 f1 = *(const float4*)(ap + kb * 32 + 4);
    bf16x8 t;
    t[0] = (short)f2bf(f0.x); t[1] = (short)f2bf(f0.y);
    t[2] = (short)f2bf(f0.z); t[3] = (short)f2bf(f0.w);
    t[4] = (short)f2bf(f1.x); t[5] = (short)f2bf(f1.y);
    t[6] = (short)f2bf(f1.z); t[7] = (short)f2bf(f1.w);
    a[kb] = t;
  }

  const int ccol = lane & 15;
  const int crow0 = row0 + (lane >> 4) * 4;
#pragma unroll
  for (int nt = 0; nt < 8; ++nt) {
    f32x4 acc = {0.f, 0.f, 0.f, 0.f};
    const bf16x8* bp =
        (const bf16x8*)(lwt + (size_t)(nt * 16 + ccol) * IN_CH + ko);
    acc = __builtin_amdgcn_mfma_f32_16x16x32_bf16(a[0], bp[0], acc, 0, 0, 0);
    acc = __builtin_amdgcn_mfma_f32_16x16x32_bf16(a[1], bp[4], acc, 0, 0, 0);
    acc = __builtin_amdgcn_mfma_f32_16x16x32_bf16(a[2], bp[8], acc, 0, 0, 0);
    acc = __builtin_amdgcn_mfma_f32_16x16x32_bf16(a[3], bp[12], acc, 0, 0, 0);
#pragma unroll
    for (int r = 0; r < 4; ++r) {
      int rr = crow0 + r;
      if (rr < N) xh[(size_t)rr * IN_CH + nt * 16 + ccol] = acc[r];
    }
  }
}

// ---------------------------------------------------------------------------
// Kernel 2: per-node scores si, sj [N,2]; wself[n] = self-loop p0.
// One wave per node; lane = channel d.
// ---------------------------------------------------------------------------
__global__ __launch_bounds__(256) void score_kernel(
    const float* __restrict__ xh, const float* __restrict__ emb,
    const float* __restrict__ att_i, const float* __restrict__ att_j,
    const float* __restrict__ att_em_i, const float* __restrict__ att_em_j,
    float2* __restrict__ si, float2* __restrict__ sj,
    float* __restrict__ wself, int N) {
  const int wave = threadIdx.x >> 6;
  const int lane = threadIdx.x & 63;
  const int n = blockIdx.x * 4 + wave;
  if (n >= N) return;

  float x0 = xh[(size_t)n * IN_CH + lane];
  float x1 = xh[(size_t)n * IN_CH + 64 + lane];
  float em = emb[(size_t)n * OUT_CH + lane];

  float v_si0 = fmaf(x0, att_i[lane], em * att_em_i[lane]);
  float v_si1 = fmaf(x1, att_i[64 + lane], em * att_em_i[64 + lane]);
  float v_sj0 = fmaf(x0, att_j[lane], em * att_em_j[lane]);
  float v_sj1 = fmaf(x1, att_j[64 + lane], em * att_em_j[64 + lane]);

#pragma unroll
  for (int off = 32; off > 0; off >>= 1) {
    v_si0 += __shfl_xor(v_si0, off, 64);
    v_si1 += __shfl_xor(v_si1, off, 64);
    v_sj0 += __shfl_xor(v_sj0, off, 64);
    v_sj1 += __shfl_xor(v_sj1, off, 64);
  }

  if (lane == 0) {
    si[n] = make_float2(v_si0, v_si1);
    sj[n] = make_float2(v_sj0, v_sj1);
    float a0 = v_si0 + v_sj0;
    float a1 = v_si1 + v_sj1;
    a0 = a0 > 0.f ? a0 : NEG_SLOPE * a0;
    a1 = a1 > 0.f ? a1 : NEG_SLOPE * a1;
    wself[n] = 1.f / (1.f + __expf(a1 - a0));
  }
}

// ---------------------------------------------------------------------------
// Kernel 3: edges — ONE fp32 atomic per edge: wsum[d] += KPACK + p0.
// (alpha0 + alpha1 == 1 exactly, so count + sum_p0 recovers both heads.)
// ---------------------------------------------------------------------------
__global__ __launch_bounds__(256) void edge_kernel(
    const int* __restrict__ esrc, const int* __restrict__ edst,
    const float2* __restrict__ si, const float2* __restrict__ sj,
    float* __restrict__ wsum, int E) {
  int e = blockIdx.x * 256 + threadIdx.x;
  if (e >= E) return;
  int s = esrc[e];
  int d = edst[e];
  float2 a = si[s];
  float2 b = sj[d];
  float a0 = a.x + b.x;
  float a1 = a.y + b.y;
  a0 = a0 > 0.f ? a0 : NEG_SLOPE * a0;
  a1 = a1 > 0.f ? a1 : NEG_SLOPE * a1;
  float p0 = 1.f / (1.f + __expf(a1 - a0));
  unsafeAtomicAdd(&wsum[d], KPACK + p0);
}

// ---------------------------------------------------------------------------
// Kernel 4: decode wsum, add self-loop, out[n,d] = 0.5*(xh0*w0 + xh1*w1).
// ---------------------------------------------------------------------------
__global__ __launch_bounds__(256) void out_kernel(
    const float* __restrict__ xh, const float* __restrict__ wsum,
    const float* __restrict__ wself, float* __restrict__ out, int N) {
  int t = blockIdx.x * 256 + threadIdx.x;
  if (t >= N * OUT_CH) return;
  int n = t >> 6;
  int d = t & 63;
  float ws = wsum[n];
  float cnt = floorf(ws * (1.0f / KPACK));
  float s0 = ws - KPACK * cnt;  // = sum of p0 over incoming edges
  float p0s = wself[n];
  float w0 = s0 + p0s;
  float w1 = (cnt - s0) + (1.f - p0s);
  float v0 = xh[(size_t)n * IN_CH + d];
  float v1 = xh[(size_t)n * IN_CH + 64 + d];
  out[t] = 0.5f * fmaf(v0, w0, v1 * w1);
}

extern "C" void kernel_launch(void* const* d_in, const int* in_sizes, int n_in,
                              void* d_out, int out_size, void* d_ws,
                              size_t ws_size, hipStream_t stream) {
  const float* x = (const float*)d_in[0];
  const float* emb = (const float*)d_in[1];
  const float* lw = (const float*)d_in[2];
  const float* att_i = (const float*)d_in[3];
  const float* att_j = (const float*)d_in[4];
  const float* att_em_i = (const float*)d_in[5];
  const float* att_em_j = (const float*)d_in[6];
  const int* esrc = (const int*)d_in[7];
  const int* edst = (const int*)d_in[8];
  float* out = (float*)d_out;

  const int N = in_sizes[0] / IN_CH;  // 50000
  const int E = in_sizes[7];          // 1600000

  char* ws = (char*)d_ws;
  float* xh = (float*)ws;                              // N*128 f32 (25.6 MB)
  float2* si = (float2*)(ws + (size_t)N * IN_CH * 4);  // N float2
  float2* sj = si + N;                                 // N float2
  float* wself = (float*)(sj + N);                     // N f32
  float* wsum = wself + N;                             // N f32
  unsigned short* lwt = (unsigned short*)(wsum + N);   // 128*128 bf16 (32 KB)

  hipMemsetAsync(wsum, 0, (size_t)N * sizeof(float), stream);
  transpose_lw_kernel<<<dim3(64), dim3(256), 0, stream>>>(lw, lwt);
  mfma_gemm_kernel<<<dim3((N + 63) / 64), dim3(256), 0, stream>>>(x, lwt, xh,
                                                                  N);
  score_kernel<<<dim3((N + 3) / 4), dim3(256), 0, stream>>>(
      xh, emb, att_i, att_j, att_em_i, att_em_j, si, sj, wself, N);
  edge_kernel<<<dim3((E + 255) / 256), dim3(256), 0, stream>>>(esrc, edst, si,
                                                               sj, wsum, E);
  out_kernel<<<dim3((N * OUT_CH + 255) / 256), dim3(256), 0, stream>>>(
      xh, wsum, wself, out, N);
}

// Round 5
// 214.180 us; speedup vs baseline: 1.4603x; 1.0955x over previous
//
#include <hip/hip_runtime.h>
#include <hip/hip_bf16.h>

#define IN_CH 128
#define OUT_CH 64
#define NEG_SLOPE 0.2f
// Packing: each edge atomically adds (KPACK + p0) to wsum[dst].
// cnt = floor(ws/KPACK), sum_p0 = ws - KPACK*cnt, w1 = cnt - sum_p0.
#define KPACK 1024.5f

typedef short bf16x8 __attribute__((ext_vector_type(8)));
typedef float f32x4 __attribute__((ext_vector_type(4)));

__device__ __forceinline__ unsigned short f2bf(float f) {
  union { float f; unsigned u; } v;
  v.f = f;
  unsigned r = v.u + 0x7FFF + ((v.u >> 16) & 1);  // RNE
  return (unsigned short)(r >> 16);
}

// ---------------------------------------------------------------------------
// Kernel 0 (prep): blocks 0..63 transpose lin_w to bf16 lwt[c][k];
// block 64 computes u_i[h][k] = sum_d lin_w[k][h*64+d]*att_i[h][d] (and u_j).
// ---------------------------------------------------------------------------
__global__ __launch_bounds__(256) void prep_kernel(
    const float* __restrict__ lw, const float* __restrict__ att_i,
    const float* __restrict__ att_j, unsigned short* __restrict__ lwt,
    float* __restrict__ u) {
  const int bid = blockIdx.x;
  const int tid = threadIdx.x;
  if (bid < 64) {
    int idx = bid * 256 + tid;  // 0..16383
    int k = idx >> 7;
    int c = idx & 127;
    lwt[(size_t)c * IN_CH + k] = f2bf(lw[idx]);
  } else {
    int k = tid & 127;
    int h = tid >> 7;
    float vi = 0.f, vj = 0.f;
#pragma unroll 8
    for (int d = 0; d < 64; ++d) {
      float wv = lw[(size_t)k * IN_CH + h * 64 + d];
      vi = fmaf(wv, att_i[h * 64 + d], vi);
      vj = fmaf(wv, att_j[h * 64 + d], vj);
    }
    u[h * 128 + k] = vi;        // u_i
    u[256 + h * 128 + k] = vj;  // u_j
  }
}

// ---------------------------------------------------------------------------
// Kernel 1 (score): si/sj straight from x and emb via u-vectors
// (x@lin_w)@att == x@(lin_w@att). Seeds wself and wsum[n]=0.
// One wave per node; lane = channel.
// ---------------------------------------------------------------------------
__global__ __launch_bounds__(256) void score_kernel(
    const float* __restrict__ x, const float* __restrict__ emb,
    const float* __restrict__ u, const float* __restrict__ aei,
    const float* __restrict__ aej, float2* __restrict__ si,
    float2* __restrict__ sj, float* __restrict__ wself,
    float* __restrict__ wsum, int N) {
  const int wave = threadIdx.x >> 6;
  const int lane = threadIdx.x & 63;
  const int n = blockIdx.x * 4 + wave;
  if (n >= N) return;

  float x0 = x[(size_t)n * IN_CH + lane];
  float x1 = x[(size_t)n * IN_CH + 64 + lane];
  float em = emb[(size_t)n * OUT_CH + lane];
  const float* ui = u;
  const float* uj = u + 256;

  float v_si0 = fmaf(x0, ui[lane], fmaf(x1, ui[64 + lane], em * aei[lane]));
  float v_si1 =
      fmaf(x0, ui[128 + lane], fmaf(x1, ui[192 + lane], em * aei[64 + lane]));
  float v_sj0 = fmaf(x0, uj[lane], fmaf(x1, uj[64 + lane], em * aej[lane]));
  float v_sj1 =
      fmaf(x0, uj[128 + lane], fmaf(x1, uj[192 + lane], em * aej[64 + lane]));

#pragma unroll
  for (int off = 32; off > 0; off >>= 1) {
    v_si0 += __shfl_xor(v_si0, off, 64);
    v_si1 += __shfl_xor(v_si1, off, 64);
    v_sj0 += __shfl_xor(v_sj0, off, 64);
    v_sj1 += __shfl_xor(v_sj1, off, 64);
  }

  if (lane == 0) {
    si[n] = make_float2(v_si0, v_si1);
    sj[n] = make_float2(v_sj0, v_sj1);
    float a0 = v_si0 + v_sj0;
    float a1 = v_si1 + v_sj1;
    a0 = a0 > 0.f ? a0 : NEG_SLOPE * a0;
    a1 = a1 > 0.f ? a1 : NEG_SLOPE * a1;
    wself[n] = 1.f / (1.f + __expf(a1 - a0));
    wsum[n] = 0.f;
  }
}

// ---------------------------------------------------------------------------
// Kernel 2 (fused): block-interleaved edge scatter (2 of 3) + MFMA gemm (1 of
// 3). Edge blocks are atomic-pipe bound (~1% VALU) so gemm rides along free.
// Edge path: 1024 edges/block, 4 per thread, ONE fp32 atomic per edge.
// Gemm path: xh = x @ lin_w via mfma_f32_16x16x32_bf16, 64 rows/block.
// ---------------------------------------------------------------------------
__global__ __launch_bounds__(256) void fused_kernel(
    const float* __restrict__ x, const unsigned short* __restrict__ lwt,
    float* __restrict__ xh, const int* __restrict__ esrc,
    const int* __restrict__ edst, const float2* __restrict__ si,
    const float2* __restrict__ sj, float* __restrict__ wsum, int N, int E,
    int GB) {
  const int bid = blockIdx.x;
  const int tid = threadIdx.x;
  const int q = bid / 3;
  const int r = bid - q * 3;

  if (r == 2) {
    // ---------------- gemm block q ----------------
    if (q >= GB) return;
    const int wave = tid >> 6;
    const int lane = tid & 63;
    const int row0 = q * 64 + wave * 16;
    int arow = row0 + (lane & 15);
    if (arow >= N) arow = N - 1;  // clamped read; stores guarded
    const int ko = (lane >> 4) * 8;

    const float* ap = x + (size_t)arow * IN_CH + ko;
    bf16x8 a[4];
#pragma unroll
    for (int kb = 0; kb < 4; ++kb) {
      float4 f0 = *(const float4*)(ap + kb * 32);
      float4 f1 = *(const float4*)(ap + kb * 32 + 4);
      bf16x8 t;
      t[0] = (short)f2bf(f0.x); t[1] = (short)f2bf(f0.y);
      t[2] = (short)f2bf(f0.z); t[3] = (short)f2bf(f0.w);
      t[4] = (short)f2bf(f1.x); t[5] = (short)f2bf(f1.y);
      t[6] = (short)f2bf(f1.z); t[7] = (short)f2bf(f1.w);
      a[kb] = t;
    }

    const int ccol = lane & 15;
    const int crow0 = row0 + (lane >> 4) * 4;
#pragma unroll
    for (int nt = 0; nt < 8; ++nt) {
      f32x4 acc = {0.f, 0.f, 0.f, 0.f};
      const bf16x8* bp =
          (const bf16x8*)(lwt + (size_t)(nt * 16 + ccol) * IN_CH + ko);
      acc = __builtin_amdgcn_mfma_f32_16x16x32_bf16(a[0], bp[0], acc, 0, 0, 0);
      acc = __builtin_amdgcn_mfma_f32_16x16x32_bf16(a[1], bp[4], acc, 0, 0, 0);
      acc = __builtin_amdgcn_mfma_f32_16x16x32_bf16(a[2], bp[8], acc, 0, 0, 0);
      acc = __builtin_amdgcn_mfma_f32_16x16x32_bf16(a[3], bp[12], acc, 0, 0, 0);
#pragma unroll
      for (int rr = 0; rr < 4; ++rr) {
        int n = crow0 + rr;
        if (n < N) xh[(size_t)n * IN_CH + nt * 16 + ccol] = acc[rr];
      }
    }
  } else {
    // ---------------- edge block ----------------
    const int e_id = bid - q;  // enumerates 0,1,2,... over r in {0,1}
    const long e0 = (long)e_id * 1024 + tid;
#pragma unroll
    for (int j = 0; j < 4; ++j) {
      long e = e0 + j * 256;
      if (e < E) {
        int s = esrc[e];
        int d = edst[e];
        float2 aa = si[s];
        float2 bb = sj[d];
        float a0 = aa.x + bb.x;
        float a1 = aa.y + bb.y;
        a0 = a0 > 0.f ? a0 : NEG_SLOPE * a0;
        a1 = a1 > 0.f ? a1 : NEG_SLOPE * a1;
        float p0 = 1.f / (1.f + __expf(a1 - a0));
        unsafeAtomicAdd(&wsum[d], KPACK + p0);
      }
    }
  }
}

// ---------------------------------------------------------------------------
// Kernel 3 (out): decode wsum, add self-loop, out = 0.5*(xh0*w0 + xh1*w1).
// float4 per thread.
// ---------------------------------------------------------------------------
__global__ __launch_bounds__(256) void out_kernel(
    const float* __restrict__ xh, const float* __restrict__ wsum,
    const float* __restrict__ wself, float* __restrict__ out, int N) {
  int t = blockIdx.x * 256 + threadIdx.x;
  if (t >= N * 16) return;
  int n = t >> 4;
  int c4 = (t & 15) << 2;
  float ws = wsum[n];
  float cnt = floorf(ws * (1.0f / KPACK));
  float s0 = ws - KPACK * cnt;  // sum of p0 over incoming edges
  float p0s = wself[n];
  float w0 = s0 + p0s;
  float w1 = (cnt - s0) + (1.f - p0s);
  float4 v0 = *(const float4*)&xh[(size_t)n * IN_CH + c4];
  float4 v1 = *(const float4*)&xh[(size_t)n * IN_CH + 64 + c4];
  float4 o;
  o.x = 0.5f * fmaf(v0.x, w0, v1.x * w1);
  o.y = 0.5f * fmaf(v0.y, w0, v1.y * w1);
  o.z = 0.5f * fmaf(v0.z, w0, v1.z * w1);
  o.w = 0.5f * fmaf(v0.w, w0, v1.w * w1);
  *(float4*)&out[(size_t)n * OUT_CH + c4] = o;
}

extern "C" void kernel_launch(void* const* d_in, const int* in_sizes, int n_in,
                              void* d_out, int out_size, void* d_ws,
                              size_t ws_size, hipStream_t stream) {
  const float* x = (const float*)d_in[0];
  const float* emb = (const float*)d_in[1];
  const float* lw = (const float*)d_in[2];
  const float* att_i = (const float*)d_in[3];
  const float* att_j = (const float*)d_in[4];
  const float* att_em_i = (const float*)d_in[5];
  const float* att_em_j = (const float*)d_in[6];
  const int* esrc = (const int*)d_in[7];
  const int* edst = (const int*)d_in[8];
  float* out = (float*)d_out;

  const int N = in_sizes[0] / IN_CH;  // 50000
  const int E = in_sizes[7];          // 1600000

  char* ws = (char*)d_ws;
  float* xh = (float*)ws;                              // N*128 f32 (25.6 MB)
  float2* si = (float2*)(ws + (size_t)N * IN_CH * 4);  // N float2
  float2* sj = si + N;                                 // N float2
  float* wself = (float*)(sj + N);                     // N f32
  float* wsum = wself + N;                             // N f32
  float* u = wsum + N;                                 // 512 f32 (u_i | u_j)
  unsigned short* lwt = (unsigned short*)(u + 512);    // 128*128 bf16 (32 KB)

  const int GB = (N + 63) / 64;       // gemm blocks
  const int EB = (E + 1023) / 1024;   // edge blocks needed
  int M = GB > (EB + 1) / 2 + 1 ? GB : (EB + 1) / 2 + 1;
  const int T = 3 * M;  // 2 edge : 1 gemm interleave

  prep_kernel<<<dim3(65), dim3(256), 0, stream>>>(lw, att_i, att_j, lwt, u);
  score_kernel<<<dim3((N + 3) / 4), dim3(256), 0, stream>>>(
      x, emb, u, att_em_i, att_em_j, si, sj, wself, wsum, N);
  fused_kernel<<<dim3(T), dim3(256), 0, stream>>>(x, lwt, xh, esrc, edst, si,
                                                  sj, wsum, N, E, GB);
  out_kernel<<<dim3((N * 16 + 255) / 256), dim3(256), 0, stream>>>(
      xh, wsum, wself, out, N);
}